// Round 11
// baseline (231.587 us; speedup 1.0000x reference)
//
#include <hip/hip_runtime.h>
#include <stdint.h>

typedef unsigned short u16;
typedef __attribute__((ext_vector_type(8))) short short8;
typedef __attribute__((ext_vector_type(4))) short short4v;
typedef __attribute__((ext_vector_type(4))) float floatx4;
typedef __attribute__((ext_vector_type(4))) int intx4;

#define B_ 2
#define N_ 2048
#define E_ 1024
#define H_ 16
#define HD_ 64
#define M_TOT (B_ * N_)   // 4096

__device__ __forceinline__ float bf2f(u16 h) {
    union { unsigned u; float f; } c; c.u = ((unsigned)h) << 16; return c.f;
}
__device__ __forceinline__ u16 f2bf(float f) {
    union { float f; unsigned u; } c; c.f = f;
    unsigned r = c.u + 0x7FFFu + ((c.u >> 16) & 1u);
    return (u16)(r >> 16);
}
__device__ __forceinline__ float silu_f(float x) { return x / (1.f + __expf(-x)); }

template <typename T> __device__ __forceinline__ void store_out(T* p, float v);
template <> __device__ __forceinline__ void store_out<u16>(u16* p, float v)    { *p = f2bf(v); }
template <> __device__ __forceinline__ void store_out<float>(float* p, float v) { *p = v; }

// Direct global->LDS 16B async copy. LDS dest = wave-uniform base + lane*16.
__device__ __forceinline__ void gll16(const void* g, void* l) {
    __builtin_amdgcn_global_load_lds(
        (const __attribute__((address_space(1))) void*)g,
        (__attribute__((address_space(3))) void*)l,
        16, 0, 0);
}

// relu(+pack) four fp32 -> 4 bf16 (round-half-up), order preserved.
__device__ __forceinline__ short4v relu_pack(floatx4 s) {
    union { float f; unsigned u; } c0, c1, c2, c3;
    c0.f = fmaxf(s[0], 0.f); c1.f = fmaxf(s[1], 0.f);
    c2.f = fmaxf(s[2], 0.f); c3.f = fmaxf(s[3], 0.f);
    unsigned lo = __builtin_amdgcn_perm(c1.u + 0x8000u, c0.u + 0x8000u, 0x07060302);
    unsigned hi = __builtin_amdgcn_perm(c3.u + 0x8000u, c2.u + 0x8000u, 0x07060302);
    union { unsigned v[2]; short4v s4; } r; r.v[0] = lo; r.v[1] = hi;
    return r.s4;
}

// ---------------------------------------------------------------------------
// fp32 -> bf16 for x (z=0, 2048 blocks) and 5 weights (z=1..5, 512 blocks).
// ---------------------------------------------------------------------------
__launch_bounds__(256, 4)
__global__ void cvt6(const float* __restrict__ s0, const float* __restrict__ s1,
                     const float* __restrict__ s2, const float* __restrict__ s3,
                     const float* __restrict__ s4, const float* __restrict__ s5,
                     u16* __restrict__ d0, u16* __restrict__ d1,
                     u16* __restrict__ d2, u16* __restrict__ d3,
                     u16* __restrict__ d4, u16* __restrict__ d5)
{
    const int z = blockIdx.z;
    if (z > 0 && blockIdx.x >= E_ * E_ / 2048) return;
    const float* src = (z == 0) ? s0 : (z == 1) ? s1 : (z == 2) ? s2
                     : (z == 3) ? s3 : (z == 4) ? s4 : s5;
    u16* dst         = (z == 0) ? d0 : (z == 1) ? d1 : (z == 2) ? d2
                     : (z == 3) ? d3 : (z == 4) ? d4 : d5;
    const int i = (blockIdx.x * 256 + threadIdx.x) * 8;
    floatx4 a = *(const floatx4*)(src + i);
    floatx4 b = *(const floatx4*)(src + i + 4);
    union { u16 h[8]; intx4 v; } o;
    o.h[0] = f2bf(a[0]); o.h[1] = f2bf(a[1]); o.h[2] = f2bf(a[2]); o.h[3] = f2bf(a[3]);
    o.h[4] = f2bf(b[0]); o.h[5] = f2bf(b[1]); o.h[6] = f2bf(b[2]); o.h[7] = f2bf(b[3]);
    *(intx4*)(dst + i) = o.v;
}

// ---------------------------------------------------------------------------
// GEMM: C[M,1024] = act( A[M,K] @ W[1024,K]^T + bias ) [*osc]
// m97 structure, BK=64 via two [128][32] sub-tile buffers per operand:
// 8 gll16 per slab, ONE barrier pair per 64 k (16 pairs total at K=1024).
// Sub-tile buffers keep conflict-free [128][32] ds_read_b128 + gll16 identity.
// ---------------------------------------------------------------------------
template <typename OutT>
__launch_bounds__(256, 2)
__global__ void gemm4(const u16* __restrict__ A,
                      const u16* __restrict__ W0, const u16* __restrict__ W1,
                      const u16* __restrict__ W2, const u16* __restrict__ W3,
                      const float* __restrict__ bi0, const float* __restrict__ bi1,
                      const float* __restrict__ bi2, const float* __restrict__ bi3,
                      OutT* __restrict__ O0, OutT* __restrict__ O1,
                      OutT* __restrict__ O2, OutT* __restrict__ O3,
                      int actmask, int scalemask, int K)
{
    __shared__ u16 a_lds[2 * 128 * 32];   // 16 KB: two k-sub-tiles
    __shared__ u16 b_lds[2 * 128 * 32];

    const int z = blockIdx.z;
    const u16* W    = (z == 0) ? W0 : (z == 1) ? W1 : (z == 2) ? W2 : W3;
    const float* Bi = (z == 0) ? bi0 : (z == 1) ? bi1 : (z == 2) ? bi2 : bi3;
    OutT* Out       = (z == 0) ? O0 : (z == 1) ? O1 : (z == 2) ? O2 : O3;
    const bool act = (actmask >> z) & 1;
    const float osc = ((scalemask >> z) & 1) ? 0.125f : 1.0f;

    const int t    = threadIdx.x;
    const int wave = t >> 6, lane = t & 63, quad = lane >> 4, l16 = lane & 15;
    const int wm = wave >> 1, wn = wave & 1;
    const int m0 = blockIdx.y * 128;
    const int n0 = blockIdx.x * 128;

    floatx4 acc[4][4];
    const floatx4 fz = {0.f, 0.f, 0.f, 0.f};
    for (int i = 0; i < 4; i++)
        for (int j = 0; j < 4; j++) acc[i][j] = fz;

    // staging map (per sub-tile): thread t -> row t/4, col (t%4)*8
    const int ar = t >> 2;            // 0..63 (row within half-tile)
    const int ac = (t & 3) * 8;       // element col
    const u16* Ag0 = A + (size_t)(m0 + ar) * K + ac;
    const u16* Ag1 = A + (size_t)(m0 + 64 + ar) * K + ac;
    const u16* Bg0 = W + (size_t)(n0 + ar) * K + ac;
    const u16* Bg1 = W + (size_t)(n0 + 64 + ar) * K + ac;
    u16* al0 = a_lds + wave * 512;          // wave-uniform base (lane*16B implicit)
    u16* al1 = a_lds + 2048 + wave * 512;   // rows 64..127
    u16* bl0 = b_lds + wave * 512;
    u16* bl1 = b_lds + 2048 + wave * 512;

    for (int k0 = 0; k0 < K; k0 += 64) {
        __syncthreads();
        for (int s = 0; s < 2; s++) {
            const int ko = k0 + s * 32, lo = s * 4096;
            gll16(Ag0 + ko, al0 + lo);
            gll16(Ag1 + ko, al1 + lo);
            gll16(Bg0 + ko, bl0 + lo);
            gll16(Bg1 + ko, bl1 + lo);
        }
        __syncthreads();   // vmcnt drained before barrier -> staging complete

        for (int s = 0; s < 2; s++) {
            const int lo = s * 4096;
            short8 af[4], bfr[4];
            for (int i = 0; i < 4; i++)
                af[i]  = *(const short8*)&a_lds[lo + (wm * 64 + i * 16 + l16) * 32 + quad * 8];
            for (int j = 0; j < 4; j++)
                bfr[j] = *(const short8*)&b_lds[lo + (wn * 64 + j * 16 + l16) * 32 + quad * 8];
            for (int i = 0; i < 4; i++)
                for (int j = 0; j < 4; j++)
                    acc[i][j] = __builtin_amdgcn_mfma_f32_16x16x32_bf16(af[i], bfr[j], acc[i][j], 0, 0, 0);
        }
    }

    float bias_v[4];
    for (int j = 0; j < 4; j++) bias_v[j] = Bi[n0 + wn * 64 + j * 16 + l16];

    for (int i = 0; i < 4; i++) {
        const int row = m0 + wm * 64 + i * 16 + quad * 4;
        for (int j = 0; j < 4; j++) {
            const int col = n0 + wn * 64 + j * 16 + l16;
            for (int r = 0; r < 4; r++) {
                float v = acc[i][j][r] + bias_v[j];
                if (act) v = silu_f(v);
                v *= osc;
                store_out<OutT>(&Out[(size_t)(row + r) * E_ + col], v);
            }
        }
    }
}

// ---------------------------------------------------------------------------
// V transpose per head: V[b][n][h*64+d] -> VT[(b*16+h)*64+d][n]
// ---------------------------------------------------------------------------
__launch_bounds__(256, 4)
__global__ void vtrans(const u16* __restrict__ V, u16* __restrict__ VT)
{
    __shared__ u16 ts[64 * 72];
    const int bh = blockIdx.y;
    const int b = bh >> 4, h = bh & 15;
    const int n0 = blockIdx.x * 64;
    const int t = threadIdx.x;
    const int r = t >> 2, seg = (t & 3) * 16;

    const u16* src = V + ((size_t)b * N_ + n0 + r) * E_ + h * HD_ + seg;
    intx4 x0 = *(const intx4*)(src);
    intx4 x1 = *(const intx4*)(src + 8);
    *(intx4*)&ts[r * 72 + seg]     = x0;
    *(intx4*)&ts[r * 72 + seg + 8] = x1;
    __syncthreads();

    union { u16 h[16]; intx4 v[2]; } buf;
    for (int j = 0; j < 16; j++) buf.h[j] = ts[(seg + j) * 72 + r];
    u16* dst = VT + ((size_t)bh * HD_ + r) * N_ + n0 + seg;
    *(intx4*)(dst)     = buf.v[0];
    *(intx4*)(dst + 8) = buf.v[1];
}

// ---------------------------------------------------------------------------
// Attention v4: O = relu(Q K^T) @ V, Q pre-scaled 1/8.
// QK: S^T = K Q^T (x32), K rows ROW-PERMUTED in LDS so two 16-key C-tiles
// relu_pack in-register into the exact x32 PV A-frag (full-rate PV).
// KTILE=128 (4 iters, 8 barrier pairs per block). V staged manually into
// padded [64][136] (conflict-free b128 B-frag reads).
// Block: 256 q (4 waves x 64 q) x (b,h) x key-chunk z (KSPLIT=4).
// ---------------------------------------------------------------------------
#define LK 72                   // K LDS stride
#define LV 136                  // V LDS stride (keys dim padded)
#define KSPLIT 4
#define KCHUNK (N_ / KSPLIT)    // 512 keys per z
#define KTILE 128

__launch_bounds__(256, 2)
__global__ void attn(const u16* __restrict__ Q, const u16* __restrict__ Kk,
                     const u16* __restrict__ VT,
                     u16* __restrict__ P0, u16* __restrict__ P1,
                     u16* __restrict__ P2, u16* __restrict__ P3)
{
    __shared__ u16 k_lds[KTILE * LK];     // row-permuted [keyslot][d]  (18.4 KB)
    __shared__ u16 v_lds[64 * LV];        // [d][key+pad]               (17.4 KB)

    const int bh = blockIdx.y;
    const int b = bh >> 4, h = bh & 15;
    const int z = blockIdx.z;
    u16* __restrict__ Oa = (z == 0) ? P0 : (z == 1) ? P1 : (z == 2) ? P2 : P3;
    const int key_base = z * KCHUNK;

    const int t = threadIdx.x;
    const int wave = t >> 6, lane = t & 63, quad = lane >> 4, l16 = lane & 15;
    const int q0 = blockIdx.x * 256 + wave * 64;
    const size_t base = (size_t)b * N_ * E_ + h * HD_;

    // Q fragments (pre-scaled 1/8): B-layout of Q^T for S^T = K Q^T.
    short8 aq[4][2];
    for (int mi = 0; mi < 4; mi++)
        for (int ks = 0; ks < 2; ks++)
            aq[mi][ks] = *(const short8*)(Q + base + (size_t)(q0 + mi * 16 + l16) * E_ + ks * 32 + quad * 8);

    floatx4 o[4][4];
    const floatx4 fz = {0.f, 0.f, 0.f, 0.f};
    for (int mi = 0; mi < 4; mi++)
        for (int nd = 0; nd < 4; nd++) o[mi][nd] = fz;

    // K staging: thread t stages key srow = t>>1 (0..127), d seg (t&1)*32.
    // Row permutation within each 64-key group (PV A-frag grouping):
    //   k6 -> (k6&32) + ((k6>>2)&1)*16 + ((k6>>3)&3)*4 + (k6&3)
    const int srow = t >> 1, sseg = (t & 1) * 32;
    const int g64 = srow >> 6, k6 = srow & 63;
    const int prow = g64 * 64 + (k6 & 32) + (((k6 >> 2) & 1) << 4)
                   + (((k6 >> 3) & 3) << 2) + (k6 & 3);
    const u16* Ksrc = Kk + base + (size_t)(key_base + srow) * E_ + sseg;
    u16* kdst = &k_lds[prow * LK + sseg];

    // V staging: thread t stages d = t>>2 (0..63), key seg (t&3)*32.
    const int vd = t >> 2, vseg = (t & 3) * 32;
    const u16* Vsrc = VT + ((size_t)bh * HD_ + vd) * N_ + key_base + vseg;
    u16* vdst = &v_lds[vd * LV + vseg];

    for (int kt = 0; kt < KCHUNK / KTILE; kt++) {
        __syncthreads();
        const u16* kg = Ksrc + (size_t)(kt * KTILE) * E_;
        const u16* vg = Vsrc + kt * KTILE;
        intx4 kv0 = *(const intx4*)(kg);
        intx4 kv1 = *(const intx4*)(kg + 8);
        intx4 kv2 = *(const intx4*)(kg + 16);
        intx4 kv3 = *(const intx4*)(kg + 24);
        intx4 vv0 = *(const intx4*)(vg);
        intx4 vv1 = *(const intx4*)(vg + 8);
        intx4 vv2 = *(const intx4*)(vg + 16);
        intx4 vv3 = *(const intx4*)(vg + 24);
        *(intx4*)(kdst)      = kv0;
        *(intx4*)(kdst + 8)  = kv1;
        *(intx4*)(kdst + 16) = kv2;
        *(intx4*)(kdst + 24) = kv3;
        *(intx4*)(vdst)      = vv0;
        *(intx4*)(vdst + 8)  = vv1;
        *(intx4*)(vdst + 16) = vv2;
        *(intx4*)(vdst + 24) = vv3;
        __syncthreads();

        for (int hf = 0; hf < 2; hf++) {        // 64-key half
            for (int g = 0; g < 2; g++) {       // 32-key group
                const int kb = hf * 64 + g * 32;
                short8 ka[2][2];
                for (int tp = 0; tp < 2; tp++)
                    for (int ks = 0; ks < 2; ks++)
                        ka[tp][ks] = *(const short8*)&k_lds[(kb + tp * 16 + l16) * LK + ks * 32 + quad * 8];
                short8 bv[4];
                for (int nd = 0; nd < 4; nd++)
                    bv[nd] = *(const short8*)&v_lds[(nd * 16 + l16) * LV + kb + quad * 8];

                for (int mi = 0; mi < 4; mi++) {
                    floatx4 c0 = __builtin_amdgcn_mfma_f32_16x16x32_bf16(ka[0][0], aq[mi][0], fz, 0, 0, 0);
                    c0 = __builtin_amdgcn_mfma_f32_16x16x32_bf16(ka[0][1], aq[mi][1], c0, 0, 0, 0);
                    floatx4 c1 = __builtin_amdgcn_mfma_f32_16x16x32_bf16(ka[1][0], aq[mi][0], fz, 0, 0, 0);
                    c1 = __builtin_amdgcn_mfma_f32_16x16x32_bf16(ka[1][1], aq[mi][1], c1, 0, 0, 0);
                    union { short4v h[2]; short8 s8; } sf;
                    sf.h[0] = relu_pack(c0);    // keys quad*8 + 0..3
                    sf.h[1] = relu_pack(c1);    // keys quad*8 + 4..7
                    for (int nd = 0; nd < 4; nd++)
                        o[mi][nd] = __builtin_amdgcn_mfma_f32_16x16x32_bf16(sf.s8, bv[nd], o[mi][nd], 0, 0, 0);
                }
            }
        }
    }

    for (int mi = 0; mi < 4; mi++)
        for (int nd = 0; nd < 4; nd++)
            for (int r = 0; r < 4; r++)
                Oa[(size_t)(b * N_ + q0 + mi * 16 + quad * 4 + r) * E_ + h * HD_ + nd * 16 + l16] =
                    f2bf(o[mi][nd][r]);
}

// ---------------------------------------------------------------------------
// LayerNorm over E=1024 of (P0+P1+P2+P3) + gate by u, emit bf16. 1 block/row.
// ---------------------------------------------------------------------------
__launch_bounds__(256, 4)
__global__ void ln_gate(const u16* __restrict__ P0, const u16* __restrict__ P1,
                        const u16* __restrict__ P2, const u16* __restrict__ P3,
                        const u16* __restrict__ U,
                        const float* __restrict__ G, const float* __restrict__ Bb,
                        u16* __restrict__ Out)
{
    const int row = blockIdx.x;
    const int t = threadIdx.x;
    const size_t idx = (size_t)row * E_ + t * 4;
    const short4v a0 = *(const short4v*)(P0 + idx);
    const short4v a1 = *(const short4v*)(P1 + idx);
    const short4v a2 = *(const short4v*)(P2 + idx);
    const short4v a3 = *(const short4v*)(P3 + idx);
    floatx4 v;
    for (int i = 0; i < 4; i++)
        v[i] = bf2f((u16)a0[i]) + bf2f((u16)a1[i]) + bf2f((u16)a2[i]) + bf2f((u16)a3[i]);
    float s  = v[0] + v[1] + v[2] + v[3];
    float ss = v[0] * v[0] + v[1] * v[1] + v[2] * v[2] + v[3] * v[3];
    for (int off = 32; off; off >>= 1) {
        s  += __shfl_down(s, off, 64);
        ss += __shfl_down(ss, off, 64);
    }
    __shared__ float red[8];
    const int wave = t >> 6, lane = t & 63;
    if (lane == 0) { red[wave] = s; red[4 + wave] = ss; }
    __syncthreads();
    const float S  = red[0] + red[1] + red[2] + red[3];
    const float SS = red[4] + red[5] + red[6] + red[7];
    const float mu  = S * (1.f / E_);
    const float var = SS * (1.f / E_) - mu * mu;
    const float rstd = rsqrtf(var + 1e-5f);

    short4v outv;
    for (int i = 0; i < 4; i++) {
        const int e = t * 4 + i;
        float y = (v[i] - mu) * rstd * G[e] + Bb[e];
        y *= bf2f(U[idx + i]);
        outv[i] = (short)f2bf(y);
    }
    *(short4v*)(Out + idx) = outv;
}

// ---------------------------------------------------------------------------
extern "C" void kernel_launch(void* const* d_in, const int* in_sizes, int n_in,
                              void* d_out, int out_size, void* d_ws, size_t ws_size,
                              hipStream_t stream)
{
    const float* x   = (const float*)d_in[0];
    const float* Wq  = (const float*)d_in[1];
    const float* bq  = (const float*)d_in[2];
    const float* Wk  = (const float*)d_in[3];
    const float* bk  = (const float*)d_in[4];
    const float* Wv  = (const float*)d_in[5];
    const float* bv  = (const float*)d_in[6];
    const float* Wu  = (const float*)d_in[7];
    const float* bu  = (const float*)d_in[8];
    const float* Wo  = (const float*)d_in[9];
    const float* bo  = (const float*)d_in[10];
    const float* lng = (const float*)d_in[11];
    const float* lnb = (const float*)d_in[12];

    char* ws = (char*)d_ws;
    u16*  qw  = (u16*)(ws);                      // 8 MB (q row-major, pre-scaled 1/8)
    u16*  kw  = (u16*)(ws + 8388608);            // 8 MB (K row-major)
    u16*  vw  = (u16*)(ws + 16777216);           // 8 MB (V row-major)
    u16*  uw  = (u16*)(ws + 25165824);           // 8 MB (u row-major)
    u16*  p0  = (u16*)(ws + 33554432);           // 8 MB bf16 attn partial z=0
    u16*  p1  = (u16*)(ws + 41943040);           // 8 MB bf16 attn partial z=1
    u16*  xb  = (u16*)(ws + 50331648);           // 8 MB x->bf16 (dead after proj)
    u16*  vt  = (u16*)(ws + 50331648);           // reuses xb region (V d-major)
    u16*  wbq = (u16*)(ws + 58720256);           // 2 MB each, bf16 weights
    u16*  wbk = (u16*)(ws + 60817408);
    u16*  wbv = (u16*)(ws + 62914560);
    u16*  wbu = (u16*)(ws + 65011712);
    u16*  wbo = (u16*)(ws + 67108864);
    u16*  gw  = (u16*)(ws);                      // reuses q buffer after attn

    float* out = (float*)d_out;
    u16*  p2  = (u16*)d_out;                     // d_out as scratch: partials z=2,3
    u16*  p3  = (u16*)d_out + 4194304;

    const dim3 blk(256, 1, 1);

    // dtype prep (x + 5 weights, one launch)
    cvt6<<<dim3(M_TOT * E_ / 2048, 1, 6), blk, 0, stream>>>(
        x, Wq, Wk, Wv, Wu, Wo, xb, wbq, wbk, wbv, wbu, wbo);
    // q,k,v,u projections (silu on v,u; q scaled 1/8)
    gemm4<u16><<<dim3(8, 32, 4), blk, 0, stream>>>(xb, wbq, wbk, wbv, wbu,
                                                   bq, bk, bv, bu,
                                                   qw, kw, vw, uw, 0xC, 0x1, E_);
    // V transpose per head (into dead xb region)
    vtrans<<<dim3(N_ / 64, B_ * H_, 1), blk, 0, stream>>>(vw, vt);
    // attention v4: 256q blocks, key-split x4, KTILE=128, full x32 PV
    attn<<<dim3(N_ / 256, B_ * H_, KSPLIT), blk, 0, stream>>>(qw, kw, vt, p0, p1, p2, p3);
    // layernorm(sum of 4 partials) + gate
    ln_gate<<<dim3(M_TOT, 1, 1), blk, 0, stream>>>(p0, p1, p2, p3, uw, lng, lnb, gw);
    // output projection -> fp32 d_out (row-major; overwrites p2/p3 scratch)
    gemm4<float><<<dim3(8, 32, 1), blk, 0, stream>>>(gw, wbo, wbo, wbo, wbo,
                                                     bo, bo, bo, bo,
                                                     out, out, out, out, 0x0, 0x0, E_);
}

// Round 12
// 230.299 us; speedup vs baseline: 1.0056x; 1.0056x over previous
//
#include <hip/hip_runtime.h>
#include <stdint.h>

typedef unsigned short u16;
typedef __attribute__((ext_vector_type(8))) short short8;
typedef __attribute__((ext_vector_type(4))) short short4v;
typedef __attribute__((ext_vector_type(4))) float floatx4;
typedef __attribute__((ext_vector_type(4))) int intx4;

#define B_ 2
#define N_ 2048
#define E_ 1024
#define H_ 16
#define HD_ 64
#define M_TOT (B_ * N_)   // 4096

__device__ __forceinline__ float bf2f(u16 h) {
    union { unsigned u; float f; } c; c.u = ((unsigned)h) << 16; return c.f;
}
__device__ __forceinline__ u16 f2bf(float f) {
    union { float f; unsigned u; } c; c.f = f;
    unsigned r = c.u + 0x7FFFu + ((c.u >> 16) & 1u);
    return (u16)(r >> 16);
}
__device__ __forceinline__ float silu_f(float x) { return x / (1.f + __expf(-x)); }

template <typename T> __device__ __forceinline__ void store_out(T* p, float v);
template <> __device__ __forceinline__ void store_out<u16>(u16* p, float v)    { *p = f2bf(v); }
template <> __device__ __forceinline__ void store_out<float>(float* p, float v) { *p = v; }

// Direct global->LDS 16B async copy. LDS dest = wave-uniform base + lane*16.
__device__ __forceinline__ void gll16(const void* g, void* l) {
    __builtin_amdgcn_global_load_lds(
        (const __attribute__((address_space(1))) void*)g,
        (__attribute__((address_space(3))) void*)l,
        16, 0, 0);
}

// relu(+pack) four fp32 -> 4 bf16 (round-half-up), order preserved.
__device__ __forceinline__ short4v relu_pack(floatx4 s) {
    union { float f; unsigned u; } c0, c1, c2, c3;
    c0.f = fmaxf(s[0], 0.f); c1.f = fmaxf(s[1], 0.f);
    c2.f = fmaxf(s[2], 0.f); c3.f = fmaxf(s[3], 0.f);
    unsigned lo = __builtin_amdgcn_perm(c1.u + 0x8000u, c0.u + 0x8000u, 0x07060302);
    unsigned hi = __builtin_amdgcn_perm(c3.u + 0x8000u, c2.u + 0x8000u, 0x07060302);
    union { unsigned v[2]; short4v s4; } r; r.v[0] = lo; r.v[1] = hi;
    return r.s4;
}

// ---------------------------------------------------------------------------
// fp32 -> bf16 for x (z=0, 2048 blocks) and 5 weights (z=1..5, 512 blocks).
// ---------------------------------------------------------------------------
__launch_bounds__(256, 4)
__global__ void cvt6(const float* __restrict__ s0, const float* __restrict__ s1,
                     const float* __restrict__ s2, const float* __restrict__ s3,
                     const float* __restrict__ s4, const float* __restrict__ s5,
                     u16* __restrict__ d0, u16* __restrict__ d1,
                     u16* __restrict__ d2, u16* __restrict__ d3,
                     u16* __restrict__ d4, u16* __restrict__ d5)
{
    const int z = blockIdx.z;
    if (z > 0 && blockIdx.x >= E_ * E_ / 2048) return;
    const float* src = (z == 0) ? s0 : (z == 1) ? s1 : (z == 2) ? s2
                     : (z == 3) ? s3 : (z == 4) ? s4 : s5;
    u16* dst         = (z == 0) ? d0 : (z == 1) ? d1 : (z == 2) ? d2
                     : (z == 3) ? d3 : (z == 4) ? d4 : d5;
    const int i = (blockIdx.x * 256 + threadIdx.x) * 8;
    floatx4 a = *(const floatx4*)(src + i);
    floatx4 b = *(const floatx4*)(src + i + 4);
    union { u16 h[8]; intx4 v; } o;
    o.h[0] = f2bf(a[0]); o.h[1] = f2bf(a[1]); o.h[2] = f2bf(a[2]); o.h[3] = f2bf(a[3]);
    o.h[4] = f2bf(b[0]); o.h[5] = f2bf(b[1]); o.h[6] = f2bf(b[2]); o.h[7] = f2bf(b[3]);
    *(intx4*)(dst + i) = o.v;
}

// ---------------------------------------------------------------------------
// Fused 2-weight projection GEMM: one block computes a 128x128 tile for TWO
// weight matrices, staging A once (A-staging halved vs 4 separate GEMMs,
// 32 MFMAs per staged A-fragment). BK=32, m97-style gll16 staging.
// z=0 -> (W0,W1)=q,k ; z=1 -> (W2,W3)=v,u. act/scale bit = z*2+zz.
// ---------------------------------------------------------------------------
__launch_bounds__(256, 2)
__global__ void gemm2z(const u16* __restrict__ A,
                       const u16* __restrict__ W0, const u16* __restrict__ W1,
                       const u16* __restrict__ W2, const u16* __restrict__ W3,
                       const float* __restrict__ bi0, const float* __restrict__ bi1,
                       const float* __restrict__ bi2, const float* __restrict__ bi3,
                       u16* __restrict__ O0, u16* __restrict__ O1,
                       u16* __restrict__ O2, u16* __restrict__ O3,
                       int actmask, int scalemask, int K)
{
    __shared__ u16 a_lds[4096];        // 8 KB
    __shared__ u16 b_lds[2][4096];     // 16 KB

    const int z = blockIdx.z;
    const u16* Wa    = (z == 0) ? W0 : W2;
    const u16* Wb    = (z == 0) ? W1 : W3;
    const float* Bia = (z == 0) ? bi0 : bi2;
    const float* Bib = (z == 0) ? bi1 : bi3;
    u16* Oa          = (z == 0) ? O0 : O2;
    u16* Ob          = (z == 0) ? O1 : O3;

    const int t    = threadIdx.x;
    const int wave = t >> 6, lane = t & 63, quad = lane >> 4, l16 = lane & 15;
    const int wm = wave >> 1, wn = wave & 1;
    const int m0 = blockIdx.y * 128;
    const int n0 = blockIdx.x * 128;

    floatx4 acc[2][4][4];
    const floatx4 fz = {0.f, 0.f, 0.f, 0.f};
    for (int zz = 0; zz < 2; zz++)
        for (int i = 0; i < 4; i++)
            for (int j = 0; j < 4; j++) acc[zz][i][j] = fz;

    // staging map: thread t -> LDS bytes [t*16, t*16+16) -> row t/4, col (t%4)*8
    const int ar = t >> 2;            // 0..63
    const int ac = (t & 3) * 8;
    const u16* Ag0  = A  + (size_t)(m0 + ar) * K + ac;
    const u16* Ag1  = A  + (size_t)(m0 + 64 + ar) * K + ac;
    const u16* Bag0 = Wa + (size_t)(n0 + ar) * K + ac;
    const u16* Bag1 = Wa + (size_t)(n0 + 64 + ar) * K + ac;
    const u16* Bbg0 = Wb + (size_t)(n0 + ar) * K + ac;
    const u16* Bbg1 = Wb + (size_t)(n0 + 64 + ar) * K + ac;
    u16* al0  = a_lds + wave * 512;
    u16* al1  = a_lds + 2048 + wave * 512;
    u16* bl00 = b_lds[0] + wave * 512;
    u16* bl01 = b_lds[0] + 2048 + wave * 512;
    u16* bl10 = b_lds[1] + wave * 512;
    u16* bl11 = b_lds[1] + 2048 + wave * 512;

    for (int k0 = 0; k0 < K; k0 += 32) {
        __syncthreads();
        gll16(Ag0 + k0, al0);
        gll16(Ag1 + k0, al1);
        gll16(Bag0 + k0, bl00);
        gll16(Bag1 + k0, bl01);
        gll16(Bbg0 + k0, bl10);
        gll16(Bbg1 + k0, bl11);
        __syncthreads();

        short8 af[4];
        for (int i = 0; i < 4; i++)
            af[i] = *(const short8*)&a_lds[(wm * 64 + i * 16 + l16) * 32 + quad * 8];
        for (int zz = 0; zz < 2; zz++) {
            short8 bfr[4];
            for (int j = 0; j < 4; j++)
                bfr[j] = *(const short8*)&b_lds[zz][(wn * 64 + j * 16 + l16) * 32 + quad * 8];
            for (int i = 0; i < 4; i++)
                for (int j = 0; j < 4; j++)
                    acc[zz][i][j] = __builtin_amdgcn_mfma_f32_16x16x32_bf16(af[i], bfr[j], acc[zz][i][j], 0, 0, 0);
        }
    }

    for (int zz = 0; zz < 2; zz++) {
        const float* Bi = zz ? Bib : Bia;
        u16* Out        = zz ? Ob : Oa;
        const bool act  = (actmask >> (z * 2 + zz)) & 1;
        const float osc = ((scalemask >> (z * 2 + zz)) & 1) ? 0.125f : 1.0f;
        float bias_v[4];
        for (int j = 0; j < 4; j++) bias_v[j] = Bi[n0 + wn * 64 + j * 16 + l16];
        for (int i = 0; i < 4; i++) {
            const int row = m0 + wm * 64 + i * 16 + quad * 4;
            for (int j = 0; j < 4; j++) {
                const int col = n0 + wn * 64 + j * 16 + l16;
                for (int r = 0; r < 4; r++) {
                    float v = acc[zz][i][j][r] + bias_v[j];
                    if (act) v = silu_f(v);
                    v *= osc;
                    Out[(size_t)(row + r) * E_ + col] = f2bf(v);
                }
            }
        }
    }
}

// ---------------------------------------------------------------------------
// GEMM (m97 structure, BK=32): out-projection. Row-major coalesced epilogue.
// ---------------------------------------------------------------------------
template <typename OutT>
__launch_bounds__(256, 2)
__global__ void gemm4(const u16* __restrict__ A, const u16* __restrict__ W,
                      const float* __restrict__ Bi, OutT* __restrict__ Out, int K)
{
    __shared__ u16 a_lds[128 * 32];
    __shared__ u16 b_lds[128 * 32];

    const int t    = threadIdx.x;
    const int wave = t >> 6, lane = t & 63, quad = lane >> 4, l16 = lane & 15;
    const int wm = wave >> 1, wn = wave & 1;
    const int m0 = blockIdx.y * 128;
    const int n0 = blockIdx.x * 128;

    floatx4 acc[4][4];
    const floatx4 fz = {0.f, 0.f, 0.f, 0.f};
    for (int i = 0; i < 4; i++)
        for (int j = 0; j < 4; j++) acc[i][j] = fz;

    const int ar = t >> 2;
    const int ac = (t & 3) * 8;
    const u16* Ag0 = A + (size_t)(m0 + ar) * K + ac;
    const u16* Ag1 = A + (size_t)(m0 + 64 + ar) * K + ac;
    const u16* Bg0 = W + (size_t)(n0 + ar) * K + ac;
    const u16* Bg1 = W + (size_t)(n0 + 64 + ar) * K + ac;
    u16* al0 = a_lds + wave * 512;
    u16* al1 = a_lds + 2048 + wave * 512;
    u16* bl0 = b_lds + wave * 512;
    u16* bl1 = b_lds + 2048 + wave * 512;

    for (int k0 = 0; k0 < K; k0 += 32) {
        __syncthreads();
        gll16(Ag0 + k0, al0);
        gll16(Ag1 + k0, al1);
        gll16(Bg0 + k0, bl0);
        gll16(Bg1 + k0, bl1);
        __syncthreads();

        short8 af[4], bfr[4];
        for (int i = 0; i < 4; i++)
            af[i]  = *(const short8*)&a_lds[(wm * 64 + i * 16 + l16) * 32 + quad * 8];
        for (int j = 0; j < 4; j++)
            bfr[j] = *(const short8*)&b_lds[(wn * 64 + j * 16 + l16) * 32 + quad * 8];
        for (int i = 0; i < 4; i++)
            for (int j = 0; j < 4; j++)
                acc[i][j] = __builtin_amdgcn_mfma_f32_16x16x32_bf16(af[i], bfr[j], acc[i][j], 0, 0, 0);
    }

    float bias_v[4];
    for (int j = 0; j < 4; j++) bias_v[j] = Bi[n0 + wn * 64 + j * 16 + l16];

    for (int i = 0; i < 4; i++) {
        const int row = m0 + wm * 64 + i * 16 + quad * 4;
        for (int j = 0; j < 4; j++) {
            const int col = n0 + wn * 64 + j * 16 + l16;
            for (int r = 0; r < 4; r++)
                store_out<OutT>(&Out[(size_t)(row + r) * E_ + col], acc[i][j][r] + bias_v[j]);
        }
    }
}

// ---------------------------------------------------------------------------
// V transpose per head: V[b][n][h*64+d] -> VT[(b*16+h)*64+d][n]
// ---------------------------------------------------------------------------
__launch_bounds__(256, 4)
__global__ void vtrans(const u16* __restrict__ V, u16* __restrict__ VT)
{
    __shared__ u16 ts[64 * 72];
    const int bh = blockIdx.y;
    const int b = bh >> 4, h = bh & 15;
    const int n0 = blockIdx.x * 64;
    const int t = threadIdx.x;
    const int r = t >> 2, seg = (t & 3) * 16;

    const u16* src = V + ((size_t)b * N_ + n0 + r) * E_ + h * HD_ + seg;
    intx4 x0 = *(const intx4*)(src);
    intx4 x1 = *(const intx4*)(src + 8);
    *(intx4*)&ts[r * 72 + seg]     = x0;
    *(intx4*)&ts[r * 72 + seg + 8] = x1;
    __syncthreads();

    union { u16 h[16]; intx4 v[2]; } buf;
    for (int j = 0; j < 16; j++) buf.h[j] = ts[(seg + j) * 72 + r];
    u16* dst = VT + ((size_t)bh * HD_ + r) * N_ + n0 + seg;
    *(intx4*)(dst)     = buf.v[0];
    *(intx4*)(dst + 8) = buf.v[1];
}

// ---------------------------------------------------------------------------
// Attention v3b: O = relu(Q K^T) @ V, Q pre-scaled 1/8.
// QK: S^T = K Q^T (x32), K rows ROW-PERMUTED (LK=72) so two 16-key C-tiles
// relu_pack in-register into the exact x32 PV A-frag (full-rate PV).
// V staged into PADDED [64][72] (row stride 144B -> 2-way banks, free;
// the r10 unpadded [64][64] had 16-way conflicts on bv b128 reads).
// Block: 256 q (4 waves x 64 q) x (b,h) x key-chunk z (KSPLIT=4), 64-key tiles.
// ---------------------------------------------------------------------------
#define LK 72
#define LV 72
#define KSPLIT 4
#define KCHUNK (N_ / KSPLIT)    // 512 keys per z

__launch_bounds__(256, 2)
__global__ void attn(const u16* __restrict__ Q, const u16* __restrict__ Kk,
                     const u16* __restrict__ VT,
                     u16* __restrict__ P0, u16* __restrict__ P1,
                     u16* __restrict__ P2, u16* __restrict__ P3)
{
    __shared__ u16 k_lds[64 * LK];    // row-permuted [keyslot][d]
    __shared__ u16 v_lds[64 * LV];    // [d][key], padded stride

    const int bh = blockIdx.y;
    const int b = bh >> 4, h = bh & 15;
    const int z = blockIdx.z;
    u16* __restrict__ Oa = (z == 0) ? P0 : (z == 1) ? P1 : (z == 2) ? P2 : P3;
    const int key_base = z * KCHUNK;

    const int t = threadIdx.x;
    const int wave = t >> 6, lane = t & 63, quad = lane >> 4, l16 = lane & 15;
    const int q0 = blockIdx.x * 256 + wave * 64;
    const size_t base = (size_t)b * N_ * E_ + h * HD_;

    // Q fragments (pre-scaled 1/8): B-layout of Q^T for S^T = K Q^T.
    short8 aq[4][2];
    for (int mi = 0; mi < 4; mi++)
        for (int ks = 0; ks < 2; ks++)
            aq[mi][ks] = *(const short8*)(Q + base + (size_t)(q0 + mi * 16 + l16) * E_ + ks * 32 + quad * 8);

    floatx4 o[4][4];
    const floatx4 fz = {0.f, 0.f, 0.f, 0.f};
    for (int mi = 0; mi < 4; mi++)
        for (int nd = 0; nd < 4; nd++) o[mi][nd] = fz;

    // K staging: thread t stages key srow = t>>2 into permuted LDS row:
    // key k -> row (k&32) + ((k>>2)&1)*16 + ((k>>3)&3)*4 + (k&3)
    const int srow = t >> 2, sseg = (t & 3) * 16;
    const int prow = (srow & 32) + (((srow >> 2) & 1) << 4)
                   + (((srow >> 3) & 3) << 2) + (srow & 3);
    const u16* Ksrc = Kk + base + (size_t)(key_base + srow) * E_ + sseg;
    u16* kdst = &k_lds[prow * LK + sseg];

    // V staging: thread t stages d = srow, key seg sseg (padded rows).
    const u16* Vsrc = VT + ((size_t)bh * HD_ + srow) * N_ + key_base + sseg;
    u16* vdst = &v_lds[srow * LV + sseg];

    for (int kt = 0; kt < KCHUNK / 64; kt++) {
        __syncthreads();
        const u16* kg = Ksrc + (size_t)(kt * 64) * E_;
        const u16* vg = Vsrc + kt * 64;
        intx4 kv0 = *(const intx4*)(kg);
        intx4 kv1 = *(const intx4*)(kg + 8);
        intx4 vv0 = *(const intx4*)(vg);
        intx4 vv1 = *(const intx4*)(vg + 8);
        *(intx4*)(kdst)     = kv0;
        *(intx4*)(kdst + 8) = kv1;
        *(intx4*)(vdst)     = vv0;
        *(intx4*)(vdst + 8) = vv1;
        __syncthreads();

        for (int g = 0; g < 2; g++) {   // 32-key group
            short8 ka[2][2];
            for (int tp = 0; tp < 2; tp++)
                for (int ks = 0; ks < 2; ks++)
                    ka[tp][ks] = *(const short8*)&k_lds[(g * 32 + tp * 16 + l16) * LK + ks * 32 + quad * 8];
            short8 bv[4];
            for (int nd = 0; nd < 4; nd++)
                bv[nd] = *(const short8*)&v_lds[(nd * 16 + l16) * LV + g * 32 + quad * 8];

            for (int mi = 0; mi < 4; mi++) {
                floatx4 c0 = __builtin_amdgcn_mfma_f32_16x16x32_bf16(ka[0][0], aq[mi][0], fz, 0, 0, 0);
                c0 = __builtin_amdgcn_mfma_f32_16x16x32_bf16(ka[0][1], aq[mi][1], c0, 0, 0, 0);
                floatx4 c1 = __builtin_amdgcn_mfma_f32_16x16x32_bf16(ka[1][0], aq[mi][0], fz, 0, 0, 0);
                c1 = __builtin_amdgcn_mfma_f32_16x16x32_bf16(ka[1][1], aq[mi][1], c1, 0, 0, 0);
                union { short4v h[2]; short8 s8; } sf;
                sf.h[0] = relu_pack(c0);    // keys quad*8 + 0..3
                sf.h[1] = relu_pack(c1);    // keys quad*8 + 4..7
                for (int nd = 0; nd < 4; nd++)
                    o[mi][nd] = __builtin_amdgcn_mfma_f32_16x16x32_bf16(sf.s8, bv[nd], o[mi][nd], 0, 0, 0);
            }
        }
    }

    for (int mi = 0; mi < 4; mi++)
        for (int nd = 0; nd < 4; nd++)
            for (int r = 0; r < 4; r++)
                Oa[(size_t)(b * N_ + q0 + mi * 16 + quad * 4 + r) * E_ + h * HD_ + nd * 16 + l16] =
                    f2bf(o[mi][nd][r]);
}

// ---------------------------------------------------------------------------
// LayerNorm over E=1024 of (P0+P1+P2+P3) + gate by u, emit bf16. 1 block/row.
// ---------------------------------------------------------------------------
__launch_bounds__(256, 4)
__global__ void ln_gate(const u16* __restrict__ P0, const u16* __restrict__ P1,
                        const u16* __restrict__ P2, const u16* __restrict__ P3,
                        const u16* __restrict__ U,
                        const float* __restrict__ G, const float* __restrict__ Bb,
                        u16* __restrict__ Out)
{
    const int row = blockIdx.x;
    const int t = threadIdx.x;
    const size_t idx = (size_t)row * E_ + t * 4;
    const short4v a0 = *(const short4v*)(P0 + idx);
    const short4v a1 = *(const short4v*)(P1 + idx);
    const short4v a2 = *(const short4v*)(P2 + idx);
    const short4v a3 = *(const short4v*)(P3 + idx);
    floatx4 v;
    for (int i = 0; i < 4; i++)
        v[i] = bf2f((u16)a0[i]) + bf2f((u16)a1[i]) + bf2f((u16)a2[i]) + bf2f((u16)a3[i]);
    float s  = v[0] + v[1] + v[2] + v[3];
    float ss = v[0] * v[0] + v[1] * v[1] + v[2] * v[2] + v[3] * v[3];
    for (int off = 32; off; off >>= 1) {
        s  += __shfl_down(s, off, 64);
        ss += __shfl_down(ss, off, 64);
    }
    __shared__ float red[8];
    const int wave = t >> 6, lane = t & 63;
    if (lane == 0) { red[wave] = s; red[4 + wave] = ss; }
    __syncthreads();
    const float S  = red[0] + red[1] + red[2] + red[3];
    const float SS = red[4] + red[5] + red[6] + red[7];
    const float mu  = S * (1.f / E_);
    const float var = SS * (1.f / E_) - mu * mu;
    const float rstd = rsqrtf(var + 1e-5f);

    short4v outv;
    for (int i = 0; i < 4; i++) {
        const int e = t * 4 + i;
        float y = (v[i] - mu) * rstd * G[e] + Bb[e];
        y *= bf2f(U[idx + i]);
        outv[i] = (short)f2bf(y);
    }
    *(short4v*)(Out + idx) = outv;
}

// ---------------------------------------------------------------------------
extern "C" void kernel_launch(void* const* d_in, const int* in_sizes, int n_in,
                              void* d_out, int out_size, void* d_ws, size_t ws_size,
                              hipStream_t stream)
{
    const float* x   = (const float*)d_in[0];
    const float* Wq  = (const float*)d_in[1];
    const float* bq  = (const float*)d_in[2];
    const float* Wk  = (const float*)d_in[3];
    const float* bk  = (const float*)d_in[4];
    const float* Wv  = (const float*)d_in[5];
    const float* bv  = (const float*)d_in[6];
    const float* Wu  = (const float*)d_in[7];
    const float* bu  = (const float*)d_in[8];
    const float* Wo  = (const float*)d_in[9];
    const float* bo  = (const float*)d_in[10];
    const float* lng = (const float*)d_in[11];
    const float* lnb = (const float*)d_in[12];

    char* ws = (char*)d_ws;
    u16*  qw  = (u16*)(ws);                      // 8 MB (q row-major, pre-scaled 1/8)
    u16*  kw  = (u16*)(ws + 8388608);            // 8 MB (K row-major)
    u16*  vw  = (u16*)(ws + 16777216);           // 8 MB (V row-major)
    u16*  uw  = (u16*)(ws + 25165824);           // 8 MB (u row-major)
    u16*  p0  = (u16*)(ws + 33554432);           // 8 MB bf16 attn partial z=0
    u16*  p1  = (u16*)(ws + 41943040);           // 8 MB bf16 attn partial z=1
    u16*  xb  = (u16*)(ws + 50331648);           // 8 MB x->bf16 (dead after proj)
    u16*  vt  = (u16*)(ws + 50331648);           // reuses xb region (V d-major)
    u16*  wbq = (u16*)(ws + 58720256);           // 2 MB each, bf16 weights
    u16*  wbk = (u16*)(ws + 60817408);
    u16*  wbv = (u16*)(ws + 62914560);
    u16*  wbu = (u16*)(ws + 65011712);
    u16*  wbo = (u16*)(ws + 67108864);
    u16*  gw  = (u16*)(ws);                      // reuses q buffer after attn

    float* out = (float*)d_out;
    u16*  p2  = (u16*)d_out;                     // d_out as scratch: partials z=2,3
    u16*  p3  = (u16*)d_out + 4194304;

    const dim3 blk(256, 1, 1);

    // dtype prep (x + 5 weights, one launch)
    cvt6<<<dim3(M_TOT * E_ / 2048, 1, 6), blk, 0, stream>>>(
        x, Wq, Wk, Wv, Wu, Wo, xb, wbq, wbk, wbv, wbu, wbo);
    // q,k,v,u projections, 2 weights per block (silu on v,u; q scaled 1/8)
    gemm2z<<<dim3(8, 32, 2), blk, 0, stream>>>(xb, wbq, wbk, wbv, wbu,
                                               bq, bk, bv, bu,
                                               qw, kw, vw, uw, 0xC, 0x1, E_);
    // V transpose per head (into dead xb region)
    vtrans<<<dim3(N_ / 64, B_ * H_, 1), blk, 0, stream>>>(vw, vt);
    // attention v3b: 256q blocks, key-split x4, full x32 PV, padded V LDS
    attn<<<dim3(N_ / 256, B_ * H_, KSPLIT), blk, 0, stream>>>(qw, kw, vt, p0, p1, p2, p3);
    // layernorm(sum of 4 partials) + gate
    ln_gate<<<dim3(M_TOT, 1, 1), blk, 0, stream>>>(p0, p1, p2, p3, uw, lng, lnb, gw);
    // output projection -> fp32 d_out (row-major; overwrites p2/p3 scratch)
    gemm4<float><<<dim3(8, 32, 1), blk, 0, stream>>>(gw, wbo, bo, out, E_);
}

// Round 13
// 225.103 us; speedup vs baseline: 1.0288x; 1.0231x over previous
//
#include <hip/hip_runtime.h>
#include <stdint.h>

typedef unsigned short u16;
typedef __attribute__((ext_vector_type(8))) short short8;
typedef __attribute__((ext_vector_type(4))) short short4v;
typedef __attribute__((ext_vector_type(4))) float floatx4;
typedef __attribute__((ext_vector_type(4))) int intx4;

#define B_ 2
#define N_ 2048
#define E_ 1024
#define H_ 16
#define HD_ 64
#define M_TOT (B_ * N_)   // 4096

__device__ __forceinline__ float bf2f(u16 h) {
    union { unsigned u; float f; } c; c.u = ((unsigned)h) << 16; return c.f;
}
__device__ __forceinline__ u16 f2bf(float f) {
    union { float f; unsigned u; } c; c.f = f;
    unsigned r = c.u + 0x7FFFu + ((c.u >> 16) & 1u);
    return (u16)(r >> 16);
}
__device__ __forceinline__ float silu_f(float x) { return x / (1.f + __expf(-x)); }

template <typename T> __device__ __forceinline__ void store_out(T* p, float v);
template <> __device__ __forceinline__ void store_out<u16>(u16* p, float v)    { *p = f2bf(v); }
template <> __device__ __forceinline__ void store_out<float>(float* p, float v) { *p = v; }

// Direct global->LDS 16B async copy. LDS dest = wave-uniform base + lane*16.
__device__ __forceinline__ void gll16(const void* g, void* l) {
    __builtin_amdgcn_global_load_lds(
        (const __attribute__((address_space(1))) void*)g,
        (__attribute__((address_space(3))) void*)l,
        16, 0, 0);
}

// relu(+pack) four fp32 -> 4 bf16 (round-half-up), order preserved.
__device__ __forceinline__ short4v relu_pack(floatx4 s) {
    union { float f; unsigned u; } c0, c1, c2, c3;
    c0.f = fmaxf(s[0], 0.f); c1.f = fmaxf(s[1], 0.f);
    c2.f = fmaxf(s[2], 0.f); c3.f = fmaxf(s[3], 0.f);
    unsigned lo = __builtin_amdgcn_perm(c1.u + 0x8000u, c0.u + 0x8000u, 0x07060302);
    unsigned hi = __builtin_amdgcn_perm(c3.u + 0x8000u, c2.u + 0x8000u, 0x07060302);
    union { unsigned v[2]; short4v s4; } r; r.v[0] = lo; r.v[1] = hi;
    return r.s4;
}

// ---------------------------------------------------------------------------
// fp32 -> bf16 for x (z=0, 2048 blocks) and 5 weights (z=1..5, 512 blocks).
// ---------------------------------------------------------------------------
__launch_bounds__(256, 4)
__global__ void cvt6(const float* __restrict__ s0, const float* __restrict__ s1,
                     const float* __restrict__ s2, const float* __restrict__ s3,
                     const float* __restrict__ s4, const float* __restrict__ s5,
                     u16* __restrict__ d0, u16* __restrict__ d1,
                     u16* __restrict__ d2, u16* __restrict__ d3,
                     u16* __restrict__ d4, u16* __restrict__ d5)
{
    const int z = blockIdx.z;
    if (z > 0 && blockIdx.x >= E_ * E_ / 2048) return;
    const float* src = (z == 0) ? s0 : (z == 1) ? s1 : (z == 2) ? s2
                     : (z == 3) ? s3 : (z == 4) ? s4 : s5;
    u16* dst         = (z == 0) ? d0 : (z == 1) ? d1 : (z == 2) ? d2
                     : (z == 3) ? d3 : (z == 4) ? d4 : d5;
    const int i = (blockIdx.x * 256 + threadIdx.x) * 8;
    floatx4 a = *(const floatx4*)(src + i);
    floatx4 b = *(const floatx4*)(src + i + 4);
    union { u16 h[8]; intx4 v; } o;
    o.h[0] = f2bf(a[0]); o.h[1] = f2bf(a[1]); o.h[2] = f2bf(a[2]); o.h[3] = f2bf(a[3]);
    o.h[4] = f2bf(b[0]); o.h[5] = f2bf(b[1]); o.h[6] = f2bf(b[2]); o.h[7] = f2bf(b[3]);
    *(intx4*)(dst + i) = o.v;
}

// ---------------------------------------------------------------------------
// GEMM (m97 structure, BK=32): C[M,1024] = act( A @ W^T + bias ) [*osc]
// blockIdx.z selects (W, bias, out, act, scale). Row-major coalesced epilogue
// ONLY (scattered epilogues cause 64x write amplification -- r7: 2 GB).
// This is the measured structural floor (r10-r12: BK=64 and 2z-fusion both
// neutral; matches learn_hip m131-m141 plateau).
// ---------------------------------------------------------------------------
template <typename OutT>
__launch_bounds__(256, 2)
__global__ void gemm4(const u16* __restrict__ A,
                      const u16* __restrict__ W0, const u16* __restrict__ W1,
                      const u16* __restrict__ W2, const u16* __restrict__ W3,
                      const float* __restrict__ bi0, const float* __restrict__ bi1,
                      const float* __restrict__ bi2, const float* __restrict__ bi3,
                      OutT* __restrict__ O0, OutT* __restrict__ O1,
                      OutT* __restrict__ O2, OutT* __restrict__ O3,
                      int actmask, int scalemask, int K)
{
    __shared__ u16 a_lds[128 * 32];   // 8 KB, unpadded (gll16 lane order)
    __shared__ u16 b_lds[128 * 32];

    const int z = blockIdx.z;
    const u16* W    = (z == 0) ? W0 : (z == 1) ? W1 : (z == 2) ? W2 : W3;
    const float* Bi = (z == 0) ? bi0 : (z == 1) ? bi1 : (z == 2) ? bi2 : bi3;
    OutT* Out       = (z == 0) ? O0 : (z == 1) ? O1 : (z == 2) ? O2 : O3;
    const bool act = (actmask >> z) & 1;
    const float osc = ((scalemask >> z) & 1) ? 0.125f : 1.0f;

    const int t    = threadIdx.x;
    const int wave = t >> 6, lane = t & 63, quad = lane >> 4, l16 = lane & 15;
    const int wm = wave >> 1, wn = wave & 1;
    const int m0 = blockIdx.y * 128;
    const int n0 = blockIdx.x * 128;

    floatx4 acc[4][4];
    const floatx4 fz = {0.f, 0.f, 0.f, 0.f};
    for (int i = 0; i < 4; i++)
        for (int j = 0; j < 4; j++) acc[i][j] = fz;

    // staging map: thread t -> LDS bytes [t*16, t*16+16) -> row t/4, col (t%4)*8
    const int ar = t >> 2;
    const int ac = (t & 3) * 8;
    const u16* Ag0 = A + (size_t)(m0 + ar) * K + ac;
    const u16* Ag1 = A + (size_t)(m0 + 64 + ar) * K + ac;
    const u16* Bg0 = W + (size_t)(n0 + ar) * K + ac;
    const u16* Bg1 = W + (size_t)(n0 + 64 + ar) * K + ac;
    u16* al0 = a_lds + wave * 512;
    u16* al1 = a_lds + 2048 + wave * 512;
    u16* bl0 = b_lds + wave * 512;
    u16* bl1 = b_lds + 2048 + wave * 512;

    for (int k0 = 0; k0 < K; k0 += 32) {
        __syncthreads();
        gll16(Ag0 + k0, al0);
        gll16(Ag1 + k0, al1);
        gll16(Bg0 + k0, bl0);
        gll16(Bg1 + k0, bl1);
        __syncthreads();

        short8 af[4], bfr[4];
        for (int i = 0; i < 4; i++)
            af[i]  = *(const short8*)&a_lds[(wm * 64 + i * 16 + l16) * 32 + quad * 8];
        for (int j = 0; j < 4; j++)
            bfr[j] = *(const short8*)&b_lds[(wn * 64 + j * 16 + l16) * 32 + quad * 8];
        for (int i = 0; i < 4; i++)
            for (int j = 0; j < 4; j++)
                acc[i][j] = __builtin_amdgcn_mfma_f32_16x16x32_bf16(af[i], bfr[j], acc[i][j], 0, 0, 0);
    }

    float bias_v[4];
    for (int j = 0; j < 4; j++) bias_v[j] = Bi[n0 + wn * 64 + j * 16 + l16];

    for (int i = 0; i < 4; i++) {
        const int row = m0 + wm * 64 + i * 16 + quad * 4;
        for (int j = 0; j < 4; j++) {
            const int col = n0 + wn * 64 + j * 16 + l16;
            for (int r = 0; r < 4; r++) {
                float v = acc[i][j][r] + bias_v[j];
                if (act) v = silu_f(v);
                v *= osc;
                store_out<OutT>(&Out[(size_t)(row + r) * E_ + col], v);
            }
        }
    }
}

// ---------------------------------------------------------------------------
// Attention v5: O = relu(Q K^T) @ V, Q pre-scaled 1/8. vtrans FUSED into
// staging (one fewer kernel launch): V read row-major coalesced, transposed
// into padded [64][72] LDS via 16 ds_write_b16/thread (bank-free: 576c==0
// mod 32, key/2 covers 32 banks 2-way).
// QK: S^T = K Q^T (x32), K rows ROW-PERMUTED (LK=72) so two 16-key C-tiles
// relu_pack in-register into the exact x32 PV A-frag (full-rate x32 PV).
// Block: 256 q (4 waves x 64 q) x (b,h) x key-chunk z (KSPLIT=4), 64-key tiles.
// ---------------------------------------------------------------------------
#define LK 72
#define LV 72
#define KSPLIT 4
#define KCHUNK (N_ / KSPLIT)    // 512 keys per z

__launch_bounds__(256, 2)
__global__ void attn(const u16* __restrict__ Q, const u16* __restrict__ Kk,
                     const u16* __restrict__ V,
                     u16* __restrict__ P0, u16* __restrict__ P1,
                     u16* __restrict__ P2, u16* __restrict__ P3)
{
    __shared__ u16 k_lds[64 * LK];    // row-permuted [keyslot][d]
    __shared__ u16 v_lds[64 * LV];    // [d][key], padded stride

    const int bh = blockIdx.y;
    const int b = bh >> 4, h = bh & 15;
    const int z = blockIdx.z;
    u16* __restrict__ Oa = (z == 0) ? P0 : (z == 1) ? P1 : (z == 2) ? P2 : P3;
    const int key_base = z * KCHUNK;

    const int t = threadIdx.x;
    const int wave = t >> 6, lane = t & 63, quad = lane >> 4, l16 = lane & 15;
    const int q0 = blockIdx.x * 256 + wave * 64;
    const size_t base = (size_t)b * N_ * E_ + h * HD_;

    // Q fragments (pre-scaled 1/8): B-layout of Q^T for S^T = K Q^T.
    short8 aq[4][2];
    for (int mi = 0; mi < 4; mi++)
        for (int ks = 0; ks < 2; ks++)
            aq[mi][ks] = *(const short8*)(Q + base + (size_t)(q0 + mi * 16 + l16) * E_ + ks * 32 + quad * 8);

    floatx4 o[4][4];
    const floatx4 fz = {0.f, 0.f, 0.f, 0.f};
    for (int mi = 0; mi < 4; mi++)
        for (int nd = 0; nd < 4; nd++) o[mi][nd] = fz;

    // K staging: thread t stages key srow = t>>2 into permuted LDS row:
    // key k -> row (k&32) + ((k>>2)&1)*16 + ((k>>3)&3)*4 + (k&3)
    const int srow = t >> 2, sseg = (t & 3) * 16;
    const int prow = (srow & 32) + (((srow >> 2) & 1) << 4)
                   + (((srow >> 3) & 3) << 2) + (srow & 3);
    const u16* Ksrc = Kk + base + (size_t)(key_base + srow) * E_ + sseg;
    u16* kdst = &k_lds[prow * LK + sseg];

    // V staging (fused transpose): read V[key=srow][d=sseg..sseg+16) coalesced,
    // write 16 b16 elems transposed into v_lds[d][key].
    const u16* Vsrc = V + base + (size_t)(key_base + srow) * E_ + sseg;

    for (int kt = 0; kt < KCHUNK / 64; kt++) {
        __syncthreads();
        const u16* kg = Ksrc + (size_t)(kt * 64) * E_;
        const u16* vg = Vsrc + (size_t)(kt * 64) * E_;
        intx4 kv0 = *(const intx4*)(kg);
        intx4 kv1 = *(const intx4*)(kg + 8);
        intx4 vv0 = *(const intx4*)(vg);
        intx4 vv1 = *(const intx4*)(vg + 8);
        *(intx4*)(kdst)     = kv0;
        *(intx4*)(kdst + 8) = kv1;
        const u16* v0p = (const u16*)&vv0;
        const u16* v1p = (const u16*)&vv1;
        for (int i = 0; i < 8; i++) {
            v_lds[(sseg + i) * LV + srow]     = v0p[i];
            v_lds[(sseg + 8 + i) * LV + srow] = v1p[i];
        }
        __syncthreads();

        for (int g = 0; g < 2; g++) {   // 32-key group
            short8 ka[2][2];
            for (int tp = 0; tp < 2; tp++)
                for (int ks = 0; ks < 2; ks++)
                    ka[tp][ks] = *(const short8*)&k_lds[(g * 32 + tp * 16 + l16) * LK + ks * 32 + quad * 8];
            short8 bv[4];
            for (int nd = 0; nd < 4; nd++)
                bv[nd] = *(const short8*)&v_lds[(nd * 16 + l16) * LV + g * 32 + quad * 8];

            for (int mi = 0; mi < 4; mi++) {
                floatx4 c0 = __builtin_amdgcn_mfma_f32_16x16x32_bf16(ka[0][0], aq[mi][0], fz, 0, 0, 0);
                c0 = __builtin_amdgcn_mfma_f32_16x16x32_bf16(ka[0][1], aq[mi][1], c0, 0, 0, 0);
                floatx4 c1 = __builtin_amdgcn_mfma_f32_16x16x32_bf16(ka[1][0], aq[mi][0], fz, 0, 0, 0);
                c1 = __builtin_amdgcn_mfma_f32_16x16x32_bf16(ka[1][1], aq[mi][1], c1, 0, 0, 0);
                union { short4v h[2]; short8 s8; } sf;
                sf.h[0] = relu_pack(c0);    // keys quad*8 + 0..3
                sf.h[1] = relu_pack(c1);    // keys quad*8 + 4..7
                for (int nd = 0; nd < 4; nd++)
                    o[mi][nd] = __builtin_amdgcn_mfma_f32_16x16x32_bf16(sf.s8, bv[nd], o[mi][nd], 0, 0, 0);
            }
        }
    }

    for (int mi = 0; mi < 4; mi++)
        for (int nd = 0; nd < 4; nd++)
            for (int r = 0; r < 4; r++)
                Oa[(size_t)(b * N_ + q0 + mi * 16 + quad * 4 + r) * E_ + h * HD_ + nd * 16 + l16] =
                    f2bf(o[mi][nd][r]);
}

// ---------------------------------------------------------------------------
// LayerNorm over E=1024 of (P0+P1+P2+P3) + gate by u, emit bf16. 1 block/row.
// ---------------------------------------------------------------------------
__launch_bounds__(256, 4)
__global__ void ln_gate(const u16* __restrict__ P0, const u16* __restrict__ P1,
                        const u16* __restrict__ P2, const u16* __restrict__ P3,
                        const u16* __restrict__ U,
                        const float* __restrict__ G, const float* __restrict__ Bb,
                        u16* __restrict__ Out)
{
    const int row = blockIdx.x;
    const int t = threadIdx.x;
    const size_t idx = (size_t)row * E_ + t * 4;
    const short4v a0 = *(const short4v*)(P0 + idx);
    const short4v a1 = *(const short4v*)(P1 + idx);
    const short4v a2 = *(const short4v*)(P2 + idx);
    const short4v a3 = *(const short4v*)(P3 + idx);
    floatx4 v;
    for (int i = 0; i < 4; i++)
        v[i] = bf2f((u16)a0[i]) + bf2f((u16)a1[i]) + bf2f((u16)a2[i]) + bf2f((u16)a3[i]);
    float s  = v[0] + v[1] + v[2] + v[3];
    float ss = v[0] * v[0] + v[1] * v[1] + v[2] * v[2] + v[3] * v[3];
    for (int off = 32; off; off >>= 1) {
        s  += __shfl_down(s, off, 64);
        ss += __shfl_down(ss, off, 64);
    }
    __shared__ float red[8];
    const int wave = t >> 6, lane = t & 63;
    if (lane == 0) { red[wave] = s; red[4 + wave] = ss; }
    __syncthreads();
    const float S  = red[0] + red[1] + red[2] + red[3];
    const float SS = red[4] + red[5] + red[6] + red[7];
    const float mu  = S * (1.f / E_);
    const float var = SS * (1.f / E_) - mu * mu;
    const float rstd = rsqrtf(var + 1e-5f);

    short4v outv;
    for (int i = 0; i < 4; i++) {
        const int e = t * 4 + i;
        float y = (v[i] - mu) * rstd * G[e] + Bb[e];
        y *= bf2f(U[idx + i]);
        outv[i] = (short)f2bf(y);
    }
    *(short4v*)(Out + idx) = outv;
}

// ---------------------------------------------------------------------------
extern "C" void kernel_launch(void* const* d_in, const int* in_sizes, int n_in,
                              void* d_out, int out_size, void* d_ws, size_t ws_size,
                              hipStream_t stream)
{
    const float* x   = (const float*)d_in[0];
    const float* Wq  = (const float*)d_in[1];
    const float* bq  = (const float*)d_in[2];
    const float* Wk  = (const float*)d_in[3];
    const float* bk  = (const float*)d_in[4];
    const float* Wv  = (const float*)d_in[5];
    const float* bv  = (const float*)d_in[6];
    const float* Wu  = (const float*)d_in[7];
    const float* bu  = (const float*)d_in[8];
    const float* Wo  = (const float*)d_in[9];
    const float* bo  = (const float*)d_in[10];
    const float* lng = (const float*)d_in[11];
    const float* lnb = (const float*)d_in[12];

    char* ws = (char*)d_ws;
    u16*  qw  = (u16*)(ws);                      // 8 MB (q row-major, pre-scaled 1/8)
    u16*  kw  = (u16*)(ws + 8388608);            // 8 MB (K row-major)
    u16*  vw  = (u16*)(ws + 16777216);           // 8 MB (V row-major)
    u16*  uw  = (u16*)(ws + 25165824);           // 8 MB (u row-major)
    u16*  p0  = (u16*)(ws + 33554432);           // 8 MB bf16 attn partial z=0
    u16*  p1  = (u16*)(ws + 41943040);           // 8 MB bf16 attn partial z=1
    u16*  xb  = (u16*)(ws + 50331648);           // 8 MB x->bf16
    u16*  wbq = (u16*)(ws + 58720256);           // 2 MB each, bf16 weights
    u16*  wbk = (u16*)(ws + 60817408);
    u16*  wbv = (u16*)(ws + 62914560);
    u16*  wbu = (u16*)(ws + 65011712);
    u16*  wbo = (u16*)(ws + 67108864);
    u16*  gw  = (u16*)(ws);                      // reuses q buffer after attn

    float* out = (float*)d_out;
    u16*  p2  = (u16*)d_out;                     // d_out as scratch: partials z=2,3
    u16*  p3  = (u16*)d_out + 4194304;

    const dim3 blk(256, 1, 1);

    // dtype prep (x + 5 weights, one launch)
    cvt6<<<dim3(M_TOT * E_ / 2048, 1, 6), blk, 0, stream>>>(
        x, Wq, Wk, Wv, Wu, Wo, xb, wbq, wbk, wbv, wbu, wbo);
    // q,k,v,u projections (silu on v,u; q scaled 1/8)
    gemm4<u16><<<dim3(8, 32, 4), blk, 0, stream>>>(xb, wbq, wbk, wbv, wbu,
                                                   bq, bk, bv, bu,
                                                   qw, kw, vw, uw, 0xC, 0x1, E_);
    // attention v5 (fused V transpose): 256q blocks, key-split x4, x32 PV
    attn<<<dim3(N_ / 256, B_ * H_, KSPLIT), blk, 0, stream>>>(qw, kw, vw, p0, p1, p2, p3);
    // layernorm(sum of 4 partials) + gate
    ln_gate<<<dim3(M_TOT, 1, 1), blk, 0, stream>>>(p0, p1, p2, p3, uw, lng, lnb, gw);
    // output projection -> fp32 d_out (row-major; overwrites p2/p3 scratch)
    gemm4<float><<<dim3(8, 32, 1), blk, 0, stream>>>(gw, wbo, wbo, wbo, wbo,
                                                     bo, bo, bo, bo,
                                                     out, out, out, out, 0x0, 0x0, E_);
}